// Round 3
// baseline (247.705 us; speedup 1.0000x reference)
//
#include <hip/hip_runtime.h>

// Backward warp, bilinear sampling. B=16, H=W=1024 (pow2, hardcoded), C=3, fp32.
// 4 pixels/thread: vectorized flow loads (2x float4), vectorized stores (3x float4),
// and fused row-pair gathers (6 contiguous floats per image row cover both x-corners).

struct __attribute__((packed, aligned(4))) R6 { float v[6]; };

__global__ __launch_bounds__(256) void backwarp_kernel(
    const float* __restrict__ image,
    const float* __restrict__ flow,
    float* __restrict__ out) {
  constexpr int H = 1024, W = 1024;
  int t = blockIdx.x * blockDim.x + threadIdx.x;
  int p0 = t << 2;                 // first of 4 pixels; W%4==0 so all 4 share a row
  int w0 = p0 & (W - 1);
  int h  = (p0 >> 10) & (H - 1);
  int b  = p0 >> 20;
  int plane = b << 20;             // b * H * W  (row y is added per-sample below)

  const float4 fA = *reinterpret_cast<const float4*>(flow + (size_t)p0 * 2);
  const float4 fB = *reinterpret_cast<const float4*>(flow + (size_t)p0 * 2 + 4);
  float fx[4] = {fA.x, fA.z, fB.x, fB.z};
  float fy[4] = {fA.y, fA.w, fB.y, fB.w};

  float res[12];
#pragma unroll
  for (int px = 0; px < 4; ++px) {
    float x = (float)(w0 + px) + fx[px];
    float y = (float)h + fy[px];
    // faithful round-trip from the reference (x/1024 == x*(1/1024) exactly)
    x = 0.5f * (2.0f * (x * (1.0f / W) - 0.5f) + 1.0f) * W;
    y = 0.5f * (2.0f * (y * (1.0f / H) - 0.5f) + 1.0f) * H;

    int x0 = (int)x;               // trunc toward zero, like astype(int32)
    int y0 = (int)y;
    int x1 = x0 + 1;
    int y1 = y0 + 1;
    x0 = min(max(x0, 0), W - 1);
    x1 = min(max(x1, 0), W - 1);
    y0 = min(max(y0, 0), H - 1);
    y1 = min(max(y1, 0), H - 1);

    float wa = ((float)x1 - x) * ((float)y1 - y);
    float wb = ((float)x1 - x) * (y - (float)y0);
    float wc = (x - (float)x0) * ((float)y1 - y);
    float wd = (x - (float)x0) * (y - (float)y0);

    // Fused gather: 6 contiguous floats starting at base_x cover pixels
    // {base_x, base_x+1}; select halves for (x0, x1) incl. border clamps.
    int bx = min(x0, W - 2);       // keep the 6-float load in-bounds of the row
    bool hiA = (x0 != bx);         // pa lives in v[3..5]
    bool hiC = (x1 != bx);         // pc lives in v[3..5]

    const R6 r0 = *reinterpret_cast<const R6*>(image + (size_t)(plane + (y0 << 10) + bx) * 3);
    const R6 r1 = *reinterpret_cast<const R6*>(image + (size_t)(plane + (y1 << 10) + bx) * 3);

#pragma unroll
    for (int c = 0; c < 3; ++c) {
      float pa = hiA ? r0.v[3 + c] : r0.v[c];
      float pc_ = hiC ? r0.v[3 + c] : r0.v[c];
      float pb = hiA ? r1.v[3 + c] : r1.v[c];
      float pd = hiC ? r1.v[3 + c] : r1.v[c];
      res[px * 3 + c] = wa * pa + wb * pb + wc * pc_ + wd * pd;
    }
  }

  float4* op = reinterpret_cast<float4*>(out + (size_t)p0 * 3);  // t*48B, 16B-aligned
  op[0] = make_float4(res[0], res[1], res[2], res[3]);
  op[1] = make_float4(res[4], res[5], res[6], res[7]);
  op[2] = make_float4(res[8], res[9], res[10], res[11]);
}

extern "C" void kernel_launch(void* const* d_in, const int* in_sizes, int n_in,
                              void* d_out, int out_size, void* d_ws, size_t ws_size,
                              hipStream_t stream) {
  const float* image = (const float*)d_in[0];
  const float* flow  = (const float*)d_in[1];
  float* out = (float*)d_out;

  const int total = 16 * 1024 * 1024;   // B*H*W
  const int block = 256;
  const int grid = total / (block * 4); // 4 px/thread, exact
  backwarp_kernel<<<grid, block, 0, stream>>>(image, flow, out);
}

// Round 4
// 156.567 us; speedup vs baseline: 1.5821x; 1.5821x over previous
//
#include <hip/hip_runtime.h>

// Backward warp, bilinear sampling. B=16, H=W=1024 (pow2, hardcoded), C=3, fp32.
// 1 px/thread (small live footprint — R3 showed 4px/thread thrashes L2),
// fused row-pair gathers (2x 24B loads replace 12 scalar gathers),
// XCD-chunked block swizzle for cross-row L2 reuse.

struct __attribute__((packed, aligned(4))) R6 { float v[6]; };

__global__ __launch_bounds__(256) void backwarp_kernel(
    const float* __restrict__ image,
    const float* __restrict__ flow,
    float* __restrict__ out) {
  constexpr int H = 1024, W = 1024;
  constexpr int NB = 16 * 1024 * 1024 / 256;   // 65536 blocks
  constexpr int CHUNK = NB / 8;

  // XCD-chunked swizzle: consecutive-dispatch blocks round-robin XCDs;
  // give each XCD a contiguous chunk so row-adjacent blocks share an L2.
  int bid = blockIdx.x;
  int sb = (bid & 7) * CHUNK + (bid >> 3);
  int idx = sb * 256 + threadIdx.x;

  int w  = idx & (W - 1);
  int h  = (idx >> 10) & (H - 1);
  int b  = idx >> 20;
  int plane = b << 20;             // b * H * W

  float2 f = *reinterpret_cast<const float2*>(flow + (size_t)idx * 2);

  float x = (float)w + f.x;
  float y = (float)h + f.y;
  // faithful round-trip from the reference (x/1024 == x*(1/1024) exactly)
  x = 0.5f * (2.0f * (x * (1.0f / W) - 0.5f) + 1.0f) * W;
  y = 0.5f * (2.0f * (y * (1.0f / H) - 0.5f) + 1.0f) * H;

  int x0 = (int)x;                 // trunc toward zero, like astype(int32)
  int y0 = (int)y;
  int x1 = x0 + 1;
  int y1 = y0 + 1;
  x0 = min(max(x0, 0), W - 1);
  x1 = min(max(x1, 0), W - 1);
  y0 = min(max(y0, 0), H - 1);
  y1 = min(max(y1, 0), H - 1);

  float wa = ((float)x1 - x) * ((float)y1 - y);
  float wb = ((float)x1 - x) * (y - (float)y0);
  float wc = (x - (float)x0) * ((float)y1 - y);
  float wd = (x - (float)x0) * (y - (float)y0);

  // Fused gather: 6 contiguous floats starting at bx cover pixels {bx, bx+1};
  // select halves for (x0, x1) including all border-clamp cases.
  int bx = min(x0, W - 2);         // keep the 6-float load in-bounds of the row
  bool hiA = (x0 != bx);           // pa lives in v[3..5]
  bool hiC = (x1 != bx);           // pc lives in v[3..5]

  const R6 r0 = *reinterpret_cast<const R6*>(image + (size_t)(plane + (y0 << 10) + bx) * 3);
  const R6 r1 = *reinterpret_cast<const R6*>(image + (size_t)(plane + (y1 << 10) + bx) * 3);

  float* o = out + (size_t)idx * 3;
#pragma unroll
  for (int c = 0; c < 3; ++c) {
    float pa  = hiA ? r0.v[3 + c] : r0.v[c];
    float pc_ = hiC ? r0.v[3 + c] : r0.v[c];
    float pb  = hiA ? r1.v[3 + c] : r1.v[c];
    float pd  = hiC ? r1.v[3 + c] : r1.v[c];
    o[c] = wa * pa + wb * pb + wc * pc_ + wd * pd;
  }
}

extern "C" void kernel_launch(void* const* d_in, const int* in_sizes, int n_in,
                              void* d_out, int out_size, void* d_ws, size_t ws_size,
                              hipStream_t stream) {
  const float* image = (const float*)d_in[0];
  const float* flow  = (const float*)d_in[1];
  float* out = (float*)d_out;

  const int total = 16 * 1024 * 1024;   // B*H*W
  const int block = 256;
  const int grid = total / block;
  backwarp_kernel<<<grid, block, 0, stream>>>(image, flow, out);
}

// Round 5
// 140.889 us; speedup vs baseline: 1.7582x; 1.1113x over previous
//
#include <hip/hip_runtime.h>

// Backward warp, bilinear sampling. B=16, H=W=1024 (pow2, hardcoded), C=3, fp32.
// 2D-tiled mapping: block = 64(w) x 4(h) pixel tile (wave = one 64-px row slice,
// 4 waves stacked vertically) -> gather footprint ~9KB fits L1, so the ~7 output
// rows that need each image line hit it in L1. Tile-column-major block order +
// XCD-chunked swizzle keeps vertically-adjacent tiles on one XCD for L2 reuse.
// Fused row-pair gathers (2x 24B loads), nontemporal stores (out never re-read).

struct __attribute__((packed, aligned(4))) R6 { float v[6]; };

__global__ __launch_bounds__(256) void backwarp_kernel(
    const float* __restrict__ image,
    const float* __restrict__ flow,
    float* __restrict__ out) {
  constexpr int H = 1024, W = 1024;
  constexpr int NB = 65536;        // 16 batches * 16 tile_x * 256 tile_y
  constexpr int CHUNK = NB / 8;

  // XCD-chunked swizzle (65536 % 8 == 0 -> bijective)
  int bid = blockIdx.x;
  int sb = (bid & 7) * CHUNK + (bid >> 3);

  // tile-column-major: consecutive sb -> vertically adjacent tiles
  int b      = sb >> 12;           // 4096 tiles per batch
  int r      = sb & 4095;
  int tile_x = r >> 8;             // [0,16)
  int tile_y = r & 255;            // [0,256)

  int lane = threadIdx.x & 63;
  int wrow = threadIdx.x >> 6;     // [0,4)

  int w = (tile_x << 6) + lane;
  int h = (tile_y << 2) + wrow;
  int idx = (b << 20) + (h << 10) + w;
  int plane = b << 20;

  float2 f = *reinterpret_cast<const float2*>(flow + (size_t)idx * 2);

  float x = (float)w + f.x;
  float y = (float)h + f.y;
  // faithful round-trip from the reference (x/1024 == x*(1/1024) exactly)
  x = 0.5f * (2.0f * (x * (1.0f / W) - 0.5f) + 1.0f) * W;
  y = 0.5f * (2.0f * (y * (1.0f / H) - 0.5f) + 1.0f) * H;

  int x0 = (int)x;                 // trunc toward zero, like astype(int32)
  int y0 = (int)y;
  int x1 = x0 + 1;
  int y1 = y0 + 1;
  x0 = min(max(x0, 0), W - 1);
  x1 = min(max(x1, 0), W - 1);
  y0 = min(max(y0, 0), H - 1);
  y1 = min(max(y1, 0), H - 1);

  float wa = ((float)x1 - x) * ((float)y1 - y);
  float wb = ((float)x1 - x) * (y - (float)y0);
  float wc = (x - (float)x0) * ((float)y1 - y);
  float wd = (x - (float)x0) * (y - (float)y0);

  // Fused gather: 6 contiguous floats starting at bx cover pixels {bx, bx+1};
  // select halves for (x0, x1) including all border-clamp cases.
  int bx = min(x0, W - 2);         // keep the 6-float load in-bounds of the row
  bool hiA = (x0 != bx);           // pa lives in v[3..5]
  bool hiC = (x1 != bx);           // pc lives in v[3..5]

  const R6 r0 = *reinterpret_cast<const R6*>(image + (size_t)(plane + (y0 << 10) + bx) * 3);
  const R6 r1 = *reinterpret_cast<const R6*>(image + (size_t)(plane + (y1 << 10) + bx) * 3);

  float* o = out + (size_t)idx * 3;
#pragma unroll
  for (int c = 0; c < 3; ++c) {
    float pa  = hiA ? r0.v[3 + c] : r0.v[c];
    float pc_ = hiC ? r0.v[3 + c] : r0.v[c];
    float pb  = hiA ? r1.v[3 + c] : r1.v[c];
    float pd  = hiC ? r1.v[3 + c] : r1.v[c];
    __builtin_nontemporal_store(wa * pa + wb * pb + wc * pc_ + wd * pd, o + c);
  }
}

extern "C" void kernel_launch(void* const* d_in, const int* in_sizes, int n_in,
                              void* d_out, int out_size, void* d_ws, size_t ws_size,
                              hipStream_t stream) {
  const float* image = (const float*)d_in[0];
  const float* flow  = (const float*)d_in[1];
  float* out = (float*)d_out;

  const int grid = 65536;          // 16M px / 256
  backwarp_kernel<<<grid, 256, 0, stream>>>(image, flow, out);
}